// Round 1
// baseline (73.615 us; speedup 1.0000x reference)
//
#include <hip/hip_runtime.h>

// TorchSTFT_75419625718337 — STFT -> (mag,phase) -> recombine -> iSTFT.
//
// Algebraic collapse (see analysis):
//   recomb == ft exactly (mag*cos(atan2(i,r)) = r, mag*sin(...) = i),
//   fwd_basis^T @ inv_basis = diag(win^2)/scale  (pinv of full-column-rank basis),
//   overlap-add then divides by the same window-sum it multiplied by.
// Net effect: out[b,0,0,t] = input_data[b,t]  (identity), up to the
// reference's own fp32 matmul roundoff (~1e-4 << 1.05e-2 threshold).
//
// Optimal implementation: a single device-to-device copy of
// B*T = 16*256000 = 4,096,000 float32 elements (16.38 MB).

extern "C" void kernel_launch(void* const* d_in, const int* in_sizes, int n_in,
                              void* d_out, int out_size, void* d_ws, size_t ws_size,
                              hipStream_t stream) {
    (void)in_sizes; (void)n_in; (void)d_ws; (void)ws_size;
    const float* input_data = (const float*)d_in[0];
    float* out = (float*)d_out;
    hipMemcpyAsync(out, input_data, (size_t)out_size * sizeof(float),
                   hipMemcpyDeviceToDevice, stream);
}